// Round 1
// baseline (245.450 us; speedup 1.0000x reference)
//
#include <hip/hip_runtime.h>

// Mobius addition broadcast: out[m,n,:] =
//   ((1 + 2*xy + nx)*B[n] + (1 - nB)*x[m]) / (1 + 2*xy + nB*nx)
// M=2048, N=1024, D=128, fp32. Output 1.07 GB -> write-BW bound.

#define M_DIM 2048
#define N_DIM 1024
#define D_DIM 128

using f4 = __attribute__((ext_vector_type(4))) float;

__global__ __launch_bounds__(256) void mobius_bcast_kernel(
    const float* __restrict__ B, const float* __restrict__ x,
    float* __restrict__ out, long long npairs)
{
    const int lane = threadIdx.x & 31;                 // lane within half-wave
    const long long hw  = ((long long)blockIdx.x * blockDim.x + threadIdx.x) >> 5;
    const long long nhw = ((long long)gridDim.x * blockDim.x) >> 5;

    for (long long p = hw; p < npairs; p += nhw) {
        const int m = (int)(p >> 10);      // N = 1024 = 2^10
        const int n = (int)(p & (N_DIM - 1));

        const f4 xv = *reinterpret_cast<const f4*>(x + (long long)m * D_DIM + lane * 4);
        const f4 bv = *reinterpret_cast<const f4*>(B + (long long)n * D_DIM + lane * 4);

        float xy  = xv.x * bv.x + xv.y * bv.y + xv.z * bv.z + xv.w * bv.w;
        float sxx = xv.x * xv.x + xv.y * xv.y + xv.z * xv.z + xv.w * xv.w;
        float sbb = bv.x * bv.x + bv.y * bv.y + bv.z * bv.z + bv.w * bv.w;

        // Reduce across the 32-lane half-wave (masks 1..16 never cross the
        // 32-lane boundary of the 64-lane wave).
        #pragma unroll
        for (int off = 1; off < 32; off <<= 1) {
            xy  += __shfl_xor(xy,  off, 64);
            sxx += __shfl_xor(sxx, off, 64);
            sbb += __shfl_xor(sbb, off, 64);
        }

        const float coefB = 1.0f + 2.0f * xy + sxx;   // 1 + 2<x,B> + |x|^2
        const float coefx = 1.0f - sbb;               // 1 - |B|^2
        const float r     = 1.0f / (1.0f + 2.0f * xy + sbb * sxx);

        f4 o;
        o.x = (coefB * bv.x + coefx * xv.x) * r;
        o.y = (coefB * bv.y + coefx * xv.y) * r;
        o.z = (coefB * bv.z + coefx * xv.z) * r;
        o.w = (coefB * bv.w + coefx * xv.w) * r;

        // Streaming 1 GB output: nontemporal so it doesn't evict B/x from L2.
        __builtin_nontemporal_store(o,
            reinterpret_cast<f4*>(out + p * D_DIM + lane * 4));
    }
}

extern "C" void kernel_launch(void* const* d_in, const int* in_sizes, int n_in,
                              void* d_out, int out_size, void* d_ws, size_t ws_size,
                              hipStream_t stream) {
    const float* B = (const float*)d_in[0];   // [N, D]
    const float* x = (const float*)d_in[1];   // [M, D]
    float* out = (float*)d_out;               // [M, N, D]

    const long long npairs = (long long)M_DIM * N_DIM;  // 2^21
    const int block = 256;
    const int grid  = 2048;  // 8 blocks/CU on 256 CUs -> full occupancy

    mobius_bcast_kernel<<<grid, block, 0, stream>>>(B, x, out, npairs);
}